// Round 1
// baseline (1091.417 us; speedup 1.0000x reference)
//
#include <hip/hip_runtime.h>
#include <math.h>

// Problem constants
constexpr int NB = 32, NL = 32, ND = 512, NHID = 512, NSTEPS = 31;
constexpr int NC5 = 2560;          // 5H
constexpr int BH = NB * NHID;      // 16384
constexpr int HSLOT_Z = 32;        // zero state slot id (33 slots total)
constexpr int NBLK = 80;           // persistent blocks (80 col tiles; all co-resident on 256 CUs)

constexpr float INV2048 = 1.f / 2048.f;

typedef _Float16 half8  __attribute__((ext_vector_type(8)));
typedef _Float16 half4  __attribute__((ext_vector_type(4)));
typedef float    f32x16 __attribute__((ext_vector_type(16)));

// ---------------- workspace layout (float offsets) ----------------
constexpr size_t OFF_GRAW = 0;                        // [31][32][2560] f32
constexpr size_t OFF_PNH  = OFF_GRAW + (size_t)31 * 32 * 2560;   // [31][32][512]
constexpr size_t OFF_PNC  = OFF_PNH + (size_t)31 * 32 * 512;
constexpr size_t OFF_PLOG = OFF_PNC + (size_t)31 * 32 * 512;     // [31][32]
constexpr size_t OFF_CST  = OFF_PLOG + 1024;          // [33][32][512] f32
constexpr size_t OFF_HHI  = OFF_CST + (size_t)33 * 32 * 512;     // halves [33][32][512]
constexpr size_t OFF_HLO  = OFF_HHI + (size_t)33 * 32 * 512 / 2;
constexpr size_t OFF_WTH  = OFF_HLO + (size_t)33 * 32 * 512 / 2; // W^T hi [n][k] halves
constexpr size_t OFF_WTL  = OFF_WTH + (size_t)NC5 * 1024 / 2;
constexpr size_t OFF_INT  = OFF_WTL + (size_t)NC5 * 1024 / 2;    // int region
constexpr size_t OFF_LIST = OFF_INT + 4096;           // 2 lists x 1024 x int4

__device__ __forceinline__ float sigf(float x) { return 1.f / (1.f + expf(-x)); }

// Device-scope sense-reversing grid barrier. Safe because all NBLK blocks are
// co-resident (NBLK=80 << 256 CUs). __syncthreads() drains each wave's stores
// (compiler emits s_waitcnt vmcnt(0) before s_barrier); the ACQ_REL RMW
// publishes the block's writes at agent scope (L2 writeback on gfx950); the
// acquire fence on exit invalidates stale L1/L2 before any post-barrier read.
__device__ __forceinline__ void grid_barrier(int* bar) {
    __syncthreads();
    if (threadIdx.x == 0) {
        const int gen = __hip_atomic_load(&bar[16], __ATOMIC_RELAXED, __HIP_MEMORY_SCOPE_AGENT);
        const int a = __hip_atomic_fetch_add(&bar[0], 1, __ATOMIC_ACQ_REL, __HIP_MEMORY_SCOPE_AGENT);
        if (a == NBLK - 1) {
            __hip_atomic_store(&bar[0], 0, __ATOMIC_RELAXED, __HIP_MEMORY_SCOPE_AGENT);
            __hip_atomic_store(&bar[16], gen + 1, __ATOMIC_RELEASE, __HIP_MEMORY_SCOPE_AGENT);
        } else {
            while (__hip_atomic_load(&bar[16], __ATOMIC_RELAXED, __HIP_MEMORY_SCOPE_AGENT) == gen)
                __builtin_amdgcn_s_sleep(2);
        }
        __builtin_amdgcn_fence(__ATOMIC_ACQUIRE, "agent");
    }
    __syncthreads();
}

// ---------------- init: indices, zero slot, step-0 list, barrier state ----------------
__global__ __launch_bounds__(256) void init_kernel(
    int* __restrict__ pidx, int* __restrict__ hidx, int* __restrict__ prevk,
    int* __restrict__ cnt, int4* __restrict__ list0,
    _Float16* __restrict__ hHi, _Float16* __restrict__ hLo, float* __restrict__ cSt,
    int* __restrict__ bar)
{
    const int blk = blockIdx.x, tid = threadIdx.x;
    if (blk < 32) {
        if (tid < 32) { pidx[blk * 32 + tid] = min(tid, 30); hidx[blk * 32 + tid] = tid; }
        if (tid == 0) prevk[blk] = -1;
        if (tid < 31) list0[tid * 32 + blk] = make_int4(blk, tid, tid, tid + 1);
    } else if (blk == 32) {
        const size_t zb = (size_t)HSLOT_Z * NB * NHID;
        for (int i = tid; i < NB * NHID; i += 256) {
            hHi[zb + i] = (_Float16)0.f;
            hLo[zb + i] = (_Float16)0.f;
            cSt[zb + i] = 0.f;
        }
    } else {
        if (tid == 0) { cnt[0] = 992; cnt[1] = 0; bar[0] = 0; bar[16] = 0; }
    }
}

// ---------------- W_comp -> transposed split fp16 planes ----------------
__global__ __launch_bounds__(256) void wsplit_kernel(
    const float* __restrict__ W, _Float16* __restrict__ Wth, _Float16* __restrict__ Wtl)
{
    __shared__ float t[32][33];
    const int n0 = blockIdx.x * 32, k0 = blockIdx.y * 32;
    const int tid = threadIdx.x;
    const int c = tid & 31, r8 = tid >> 5;
#pragma unroll
    for (int p = 0; p < 4; ++p) {
        int r = p * 8 + r8;
        t[r][c] = W[(size_t)(k0 + r) * NC5 + n0 + c];
    }
    __syncthreads();
    const int nl = tid >> 3, k4 = (tid & 7) * 4;
    half4 vh, vl;
#pragma unroll
    for (int i = 0; i < 4; ++i) {
        float v = t[k4 + i][nl];
        _Float16 hh = (_Float16)v;
        vh[i] = hh;
        vl[i] = (_Float16)((v - (float)hh) * 2048.f);
    }
    size_t o = (size_t)(n0 + nl) * 1024 + k0 + k4;
    *(half4*)&Wth[o] = vh;
    *(half4*)&Wtl[o] = vl;
}

// ---------------- word GEMM: leaves -> state slots 0..31 ----------------
__global__ __launch_bounds__(256) void word_gemm64(
    const float* __restrict__ A, const float* __restrict__ W,
    const float* __restrict__ bias,
    _Float16* __restrict__ hi0, _Float16* __restrict__ lo0,
    float* __restrict__ cst, float* __restrict__ out)
{
    const int m0 = blockIdx.x * 64;
    const int n0 = blockIdx.y * 64;
    const int tid = threadIdx.x;
    const int tx = tid & 15, ty = tid >> 4;
    __shared__ float As[16][64];
    __shared__ float Bs[16][64];
    float acc[4][4];
#pragma unroll
    for (int i = 0; i < 4; ++i)
#pragma unroll
        for (int j = 0; j < 4; ++j) acc[i][j] = 0.f;

    for (int kt = 0; kt < ND; kt += 16) {
        {
            int row = tid >> 2, kq = tid & 3;
            float4 v = *(const float4*)(A + (size_t)(m0 + row) * ND + kt + kq * 4);
            As[kq * 4 + 0][row] = v.x;
            As[kq * 4 + 1][row] = v.y;
            As[kq * 4 + 2][row] = v.z;
            As[kq * 4 + 3][row] = v.w;
            int kr = tid >> 4, nq = tid & 15;
            float4 vb = *(const float4*)(W + (size_t)(kt + kr) * 1024 + n0 + nq * 4);
            *(float4*)&Bs[kr][nq * 4] = vb;
        }
        __syncthreads();
#pragma unroll
        for (int kk = 0; kk < 16; ++kk) {
            float a0 = As[kk][ty * 4 + 0], a1 = As[kk][ty * 4 + 1];
            float a2 = As[kk][ty * 4 + 2], a3 = As[kk][ty * 4 + 3];
            float4 bv = *(float4*)&Bs[kk][tx * 4];
            acc[0][0] = fmaf(a0, bv.x, acc[0][0]); acc[0][1] = fmaf(a0, bv.y, acc[0][1]);
            acc[0][2] = fmaf(a0, bv.z, acc[0][2]); acc[0][3] = fmaf(a0, bv.w, acc[0][3]);
            acc[1][0] = fmaf(a1, bv.x, acc[1][0]); acc[1][1] = fmaf(a1, bv.y, acc[1][1]);
            acc[1][2] = fmaf(a1, bv.z, acc[1][2]); acc[1][3] = fmaf(a1, bv.w, acc[1][3]);
            acc[2][0] = fmaf(a2, bv.x, acc[2][0]); acc[2][1] = fmaf(a2, bv.y, acc[2][1]);
            acc[2][2] = fmaf(a2, bv.z, acc[2][2]); acc[2][3] = fmaf(a2, bv.w, acc[2][3]);
            acc[3][0] = fmaf(a3, bv.x, acc[3][0]); acc[3][1] = fmaf(a3, bv.y, acc[3][1]);
            acc[3][2] = fmaf(a3, bv.z, acc[3][2]); acc[3][3] = fmaf(a3, bv.w, acc[3][3]);
        }
        __syncthreads();
    }
    float* nodes = out + 2 * BH;
#pragma unroll
    for (int i = 0; i < 4; ++i) {
        int r = m0 + ty * 4 + i;
        int b = r >> 5, l = r & 31;
#pragma unroll
        for (int jn = 0; jn < 4; ++jn) {
            int n = n0 + tx * 4 + jn;
            float v = acc[i][jn] + bias[n];
            if (n < NHID) {
                size_t si = ((size_t)l * NB + b) * NHID + n;
                _Float16 hh = (_Float16)v;
                hi0[si] = hh;
                lo0[si] = (_Float16)((v - (float)hh) * 2048.f);
                nodes[((size_t)b * 63 + l) * NHID + n] = v;
            } else {
                cst[((size_t)l * NB + b) * NHID + (n - NHID)] = v;
            }
        }
    }
}

// ---------------- persistent kernel: all 31 steps in one dispatch ----------------
// 80 blocks x 256 threads. Per step: GEMM phase (every block owns one 32-col
// tile of W^T, loops over all row tiles; W-panel chunk hoisted to 128 VGPRs,
// fine at 1 block/CU) -> grid barrier -> update phase (blocks 0..31, one batch
// each) -> grid barrier. Arithmetic identical to the previous multi-kernel
// version; only synchronization changed.
__global__ __launch_bounds__(256, 1) void tree_loop(
    _Float16* __restrict__ hHi, _Float16* __restrict__ hLo,
    const _Float16* __restrict__ Wth, const _Float16* __restrict__ Wtl,
    float* __restrict__ graw, const float* __restrict__ bias,
    const float* __restrict__ q, const int* __restrict__ len,
    float* __restrict__ pnh, float* __restrict__ pnc, float* __restrict__ plog,
    float* __restrict__ cSt, int* __restrict__ pidx, int* __restrict__ hidx,
    int* __restrict__ prevk, int4* __restrict__ list0, int4* __restrict__ list1,
    int* __restrict__ cnt, int* __restrict__ bar, float* __restrict__ out)
{
    const int nt = blockIdx.x;             // col tile 0..79
    const int tid = threadIdx.x;
    const int kw = tid >> 6;               // wave 0..3 = K chunk
    const int lane = tid & 63;
    const int l5 = lane >> 5, ln = lane & 31;

    __shared__ float red[4][32][32];       // 16 KB cross-wave reduce
    __shared__ int s_pidx[32], s_hidx[32];
    __shared__ float lred[4];
    __shared__ int sk;

    const _Float16* bHiP = Wth + (size_t)(nt * 32 + ln) * 1024 + (kw << 8) + l5 * 8;
    const _Float16* bLoP = Wtl + (size_t)(nt * 32 + ln) * 1024 + (kw << 8) + l5 * 8;

    for (int step = 0; step < NSTEPS; ++step) {
        const int p = step & 1;
        const int4* list = p ? list1 : list0;
        int4* lnxt = p ? list0 : list1;
        int* cnt_next = cnt + (1 - p);

        const int count = cnt[p];
        if (nt == 0 && tid == 0) *cnt_next = 0;

        // ---- GEMM phase: raw gates for all listed fresh pairs ----
        if (count > 0) {
            half8 Bh[16], Bl[16];          // wave's W^T chunk: 32 cols x 256 K, both planes
#pragma unroll
            for (int ks = 0; ks < 16; ++ks) {
                Bh[ks] = *(const half8*)(bHiP + ks * 16);
                Bl[ks] = *(const half8*)(bLoP + ks * 16);
            }
            const int nmt = (count + 31) >> 5;
            for (int mt = 0; mt < nmt; ++mt) {
                const int rc = min(mt * 32 + ln, count - 1);
                const int4 d = list[rc];   // {b, slot, left, right}
                const int hs = (kw < 2) ? d.z : d.w;
                const int koff = ((kw & 1) << 8) + l5 * 8;
                const _Float16* aHiP = hHi + ((size_t)hs * NB + d.x) * NHID + koff;
                const _Float16* aLoP = hLo + ((size_t)hs * NB + d.x) * NHID + koff;
                f32x16 acc1 = (f32x16)0.f, acc2 = (f32x16)0.f;
#pragma unroll
                for (int ks = 0; ks < 16; ++ks) {
                    half8 Ah = *(const half8*)(aHiP + ks * 16);
                    half8 Al = *(const half8*)(aLoP + ks * 16);
                    acc1 = __builtin_amdgcn_mfma_f32_32x32x16_f16(Ah, Bh[ks], acc1, 0, 0, 0);
                    acc2 = __builtin_amdgcn_mfma_f32_32x32x16_f16(Ah, Bl[ks], acc2, 0, 0, 0);
                    acc2 = __builtin_amdgcn_mfma_f32_32x32x16_f16(Al, Bh[ks], acc2, 0, 0, 0);
                }
                // cross-wave reduce. C/D: col=lane&31, row=(a&3)+8*(a>>2)+4*(lane>>5)
#pragma unroll
                for (int a = 0; a < 16; ++a) {
                    int row = (a & 3) + 8 * (a >> 2) + 4 * l5;
                    red[kw][row][ln] = acc1[a] + acc2[a] * INV2048;
                }
                __syncthreads();
                {
                    const int row = tid >> 3, c0 = (tid & 7) * 4;
                    if (mt * 32 + row < count) {
                        const int4 dr = list[mt * 32 + row];
                        float4 s;
                        s.x = (red[0][row][c0+0] + red[1][row][c0+0]) + (red[2][row][c0+0] + red[3][row][c0+0]);
                        s.y = (red[0][row][c0+1] + red[1][row][c0+1]) + (red[2][row][c0+1] + red[3][row][c0+1]);
                        s.z = (red[0][row][c0+2] + red[1][row][c0+2]) + (red[2][row][c0+2] + red[3][row][c0+2]);
                        s.w = (red[0][row][c0+3] + red[1][row][c0+3]) + (red[2][row][c0+3] + red[3][row][c0+3]);
                        *(float4*)&graw[((size_t)dr.y * NB + dr.x) * NC5 + nt * 32 + c0] = s;
                    }
                }
                __syncthreads();           // red reused next row tile
            }
        }

        grid_barrier(bar);

        // ---- UPDATE phase: blocks 0..31, one batch each ----
        if (nt < NB) {
            const int b = nt;
            if (tid < 32) { s_pidx[tid] = pidx[b * 32 + tid]; s_hidx[tid] = hidx[b * 32 + tid]; }
            const int pk = prevk[b];
            __syncthreads();

            // Phase A: activate fresh pairs (step 0: all 31; else <=2 from prevk)
            int nf;
            if (step == 0) nf = 31; else if (pk < 0) nf = 0; else nf = (pk >= 1) ? 2 : 1;
            for (int f = 0; f < nf; ++f) {
                const int j = (step == 0) ? f : (pk - (nf - 1) + f);
                const int slot = s_pidx[j];
                const int ls = s_hidx[j];
                const int rs = s_hidx[j + 1];
                const float* gr = graw + ((size_t)slot * NB + b) * NC5;
                const float* clp = cSt + ((size_t)ls * NB + b) * NHID;
                const float* crp = cSt + ((size_t)rs * NB + b) * NHID;
                float lpart = 0.f;
                for (int h = tid; h < NHID; h += 256) {
                    float ig = gr[h]          + bias[h];
                    float fl = gr[512 + h]    + bias[512 + h];
                    float fr = gr[1024 + h]   + bias[1024 + h];
                    float u  = gr[1536 + h]   + bias[1536 + h];
                    float o  = gr[2048 + h]   + bias[2048 + h];
                    float cl = clp[h], cr = crp[h];
                    float c  = cl * sigf(fl + 1.f) + cr * sigf(fr + 1.f) + tanhf(u) * sigf(ig);
                    float hh = sigf(o) * tanhf(c);
                    size_t po = ((size_t)slot * NB + b) * NHID + h;
                    pnh[po] = hh;
                    pnc[po] = c;
                    lpart = fmaf(hh, q[h], lpart);
                }
#pragma unroll
                for (int off = 32; off > 0; off >>= 1) lpart += __shfl_down(lpart, off);
                if ((tid & 63) == 0) lred[tid >> 6] = lpart;
                __syncthreads();
                if (tid == 0) plog[(size_t)slot * NB + b] = (lred[0] + lred[1]) + (lred[2] + lred[3]);
                __syncthreads();
            }

            // Phase B: argmax over j < actb (first-index tie-break)
            const int actb = len[b] - 1 - step;
            const int merge = actb >= 1;
            if (tid < 64) {
                float v = -1e30f;
                int idx = tid;
                if (tid < actb && tid < 31) v = plog[(size_t)s_pidx[tid] * NB + b];
#pragma unroll
                for (int off = 32; off > 0; off >>= 1) {
                    float ov = __shfl_down(v, off);
                    int   oi = __shfl_down(idx, off);
                    if (ov > v || (ov == v && oi < idx)) { v = ov; idx = oi; }
                }
                if (tid == 0) sk = idx;
            }
            __syncthreads();
            const int k = sk;
            const int last = (step == NSTEPS - 1);

            // Phase C: node output, new-node state write, final hf/cf
            float* noderow = out + 2 * BH + ((size_t)b * 63 + 32 + step) * NHID;
            if (merge) {
                const int kslot = s_pidx[k];
                const int ns = s_hidx[k];
                for (int h = tid; h < NHID; h += 256) {
                    size_t po = ((size_t)kslot * NB + b) * NHID + h;
                    float x = pnh[po], cc = pnc[po];
                    _Float16 hh = (_Float16)x;
                    size_t so = ((size_t)ns * NB + b) * NHID + h;
                    hHi[so] = hh;
                    hLo[so] = (_Float16)((x - (float)hh) * 2048.f);
                    cSt[so] = cc;
                    noderow[h] = x;
                    if (last) { out[b * NHID + h] = x; out[BH + b * NHID + h] = cc; }
                }
            } else {
                const int s0p = s_pidx[0], s0h = s_hidx[0];
                for (int h = tid; h < NHID; h += 256) {
                    if (!last) {
                        noderow[h] = pnh[((size_t)s0p * NB + b) * NHID + h];
                    } else {
                        size_t so = ((size_t)s0h * NB + b) * NHID + h;
                        float x = (float)hHi[so] + (float)hLo[so] * INV2048;
                        noderow[h] = x;
                        out[b * NHID + h] = x;
                        out[BH + b * NHID + h] = cSt[so];
                    }
                }
            }

            // Phase D: index shifts + next fresh list
            if (tid == 0) {
                if (merge) {
                    for (int j2 = k + 1; j2 <= 29; ++j2) pidx[b * 32 + j2] = s_pidx[j2 + 1];
                    if (k < 30) pidx[b * 32 + 30] = s_pidx[k + 1];
                    for (int pp = k + 1; pp <= 30; ++pp) hidx[b * 32 + pp] = s_hidx[pp + 1];
                    hidx[b * 32 + 31] = HSLOT_Z;
                    prevk[b] = k;
                    const int nd = (k >= 1) ? 2 : 1;
                    int base = atomicAdd(cnt_next, nd);
                    if (k >= 1)
                        lnxt[base++] = make_int4(b, s_pidx[k - 1], s_hidx[k - 1], s_hidx[k]);
                    lnxt[base] = make_int4(b, s_pidx[k], s_hidx[k],
                                           (k + 2 <= 31) ? s_hidx[k + 2] : HSLOT_Z);
                } else {
                    prevk[b] = -1;
                }
            }
        }

        grid_barrier(bar);
    }
}

extern "C" void kernel_launch(void* const* d_in, const int* in_sizes, int n_in,
                              void* d_out, int out_size, void* d_ws, size_t ws_size,
                              hipStream_t stream) {
    const float* inp    = (const float*)d_in[0];
    const int*   length = (const int*)d_in[1];
    const float* W_word = (const float*)d_in[2];
    const float* b_word = (const float*)d_in[3];
    const float* W_comp = (const float*)d_in[4];
    const float* b_comp = (const float*)d_in[5];
    const float* q      = (const float*)d_in[6];
    float* out = (float*)d_out;
    float* ws  = (float*)d_ws;

    float*     graw = ws + OFF_GRAW;
    float*     pnh  = ws + OFF_PNH;
    float*     pnc  = ws + OFF_PNC;
    float*     plog = ws + OFF_PLOG;
    float*     cSt  = ws + OFF_CST;
    _Float16*  hHi  = (_Float16*)(ws + OFF_HHI);
    _Float16*  hLo  = (_Float16*)(ws + OFF_HLO);
    _Float16*  Wth  = (_Float16*)(ws + OFF_WTH);
    _Float16*  Wtl  = (_Float16*)(ws + OFF_WTL);
    int*       ireg = (int*)(ws + OFF_INT);
    int*       pidx = ireg;            // 32*32
    int*       hidx = ireg + 1024;     // 32*32
    int*       prevk = ireg + 2048;    // 32
    int*       cnt  = ireg + 2080;     // 2
    int*       bar  = ireg + 2112;     // barrier: [0]=count, [16]=generation
    int4*      list0 = (int4*)(ws + OFF_LIST);
    int4*      list1 = list0 + 1024;

    init_kernel<<<34, 256, 0, stream>>>(pidx, hidx, prevk, cnt, list0, hHi, hLo, cSt, bar);
    wsplit_kernel<<<dim3(NC5 / 32, 1024 / 32), 256, 0, stream>>>(W_comp, Wth, Wtl);
    word_gemm64<<<dim3(16, 16), 256, 0, stream>>>(inp, W_word, b_word,
                                                  hHi, hLo, cSt, out);
    tree_loop<<<NBLK, 256, 0, stream>>>(hHi, hLo, Wth, Wtl, graw, b_comp, q, length,
                                        pnh, pnc, plog, cSt, pidx, hidx, prevk,
                                        list0, list1, cnt, bar, out);
}

// Round 2
// 975.780 us; speedup vs baseline: 1.1185x; 1.1185x over previous
//
#include <hip/hip_runtime.h>
#include <math.h>

// Problem constants
constexpr int NB = 32, NL = 32, ND = 512, NHID = 512, NSTEPS = 31;
constexpr int NC5 = 2560;          // 5H
constexpr int BH = NB * NHID;      // 16384
constexpr int HSLOT_Z = 32;        // zero state slot id (33 slots total)
constexpr int NBLK = 160;          // 80 col tiles x 2 row halves; all co-resident (<=256 CUs)

constexpr float INV2048 = 1.f / 2048.f;

typedef _Float16 half8  __attribute__((ext_vector_type(8)));
typedef _Float16 half4  __attribute__((ext_vector_type(4)));
typedef float    f32x16 __attribute__((ext_vector_type(16)));

// ---------------- workspace layout (float offsets) ----------------
constexpr size_t OFF_GRAW = 0;                        // [31][32][2560] f32
constexpr size_t OFF_PNH  = OFF_GRAW + (size_t)31 * 32 * 2560;   // [31][32][512]
constexpr size_t OFF_PNC  = OFF_PNH + (size_t)31 * 32 * 512;
constexpr size_t OFF_PLOG = OFF_PNC + (size_t)31 * 32 * 512;     // [31][32] (unused now)
constexpr size_t OFF_CST  = OFF_PLOG + 1024;          // [33][32][512] f32
constexpr size_t OFF_HHI  = OFF_CST + (size_t)33 * 32 * 512;     // halves [33][32][512]
constexpr size_t OFF_HLO  = OFF_HHI + (size_t)33 * 32 * 512 / 2;
constexpr size_t OFF_WTH  = OFF_HLO + (size_t)33 * 32 * 512 / 2; // W^T hi [n][k] halves
constexpr size_t OFF_WTL  = OFF_WTH + (size_t)NC5 * 1024 / 2;
constexpr size_t OFF_INT  = OFF_WTL + (size_t)NC5 * 1024 / 2;    // int region (4096 ints)
constexpr size_t OFF_LIST = OFF_INT + 4096;           // 2 lists x 1024 x int4

// int-region layout: [0..1]=cnt ping-pong, [16]=generation, [32 + 16*blk]=flags
constexpr int IR_CNT  = 0;
constexpr int IR_GEN  = 16;
constexpr int IR_FLAG = 32;

__device__ __forceinline__ float sigf(float x) { return 1.f / (1.f + expf(-x)); }

// Flag-array grid barrier (monotonic epoch). Each block release-stores its own
// cacheline-padded flag; block 0's threads poll all flags in parallel, then
// broadcast a generation word; everyone acquire-spins on the generation.
// No same-address atomic serialization. Requires all NBLK blocks co-resident
// (NBLK=160 <= 256 CUs, __launch_bounds__(256,1)).
__device__ __forceinline__ void grid_barrier(int* flags, int* gen, int target) {
    __syncthreads();
    if (threadIdx.x == 0) {
        __builtin_amdgcn_fence(__ATOMIC_RELEASE, "agent");   // publish this block's stores
        __hip_atomic_store(&flags[blockIdx.x * 16], target, __ATOMIC_RELAXED,
                           __HIP_MEMORY_SCOPE_AGENT);
    }
    if (blockIdx.x == 0) {
        for (int i = threadIdx.x; i < NBLK; i += 256) {
            while (__hip_atomic_load(&flags[i * 16], __ATOMIC_RELAXED,
                                     __HIP_MEMORY_SCOPE_AGENT) < target)
                __builtin_amdgcn_s_sleep(1);
        }
        __syncthreads();
        if (threadIdx.x == 0)
            __hip_atomic_store(gen, target, __ATOMIC_RELAXED, __HIP_MEMORY_SCOPE_AGENT);
    }
    if (threadIdx.x == 0) {
        while (__hip_atomic_load(gen, __ATOMIC_RELAXED, __HIP_MEMORY_SCOPE_AGENT) < target)
            __builtin_amdgcn_s_sleep(1);
        __builtin_amdgcn_fence(__ATOMIC_ACQUIRE, "agent");   // make others' stores visible
    }
    __syncthreads();
}

// ---------------- init: zero slot, step-0 list, sync/int region ----------------
__global__ __launch_bounds__(256) void init_kernel(
    int* __restrict__ ireg, int4* __restrict__ list0,
    _Float16* __restrict__ hHi, _Float16* __restrict__ hLo, float* __restrict__ cSt)
{
    const int blk = blockIdx.x, tid = threadIdx.x;
    if (blk < 32) {
        if (tid < 31) list0[tid * 32 + blk] = make_int4(blk, tid, tid, tid + 1);
    } else if (blk == 32) {
        const size_t zb = (size_t)HSLOT_Z * NB * NHID;
        for (int i = tid; i < NB * NHID; i += 256) {
            hHi[zb + i] = (_Float16)0.f;
            hLo[zb + i] = (_Float16)0.f;
            cSt[zb + i] = 0.f;
        }
    } else {
        for (int i = tid; i < 4096; i += 256) ireg[i] = 0;
        __syncthreads();
        if (tid == 0) { ireg[IR_CNT] = 992; ireg[IR_CNT + 1] = 0; }
    }
}

// ---------------- W_comp -> transposed split fp16 planes ----------------
__global__ __launch_bounds__(256) void wsplit_kernel(
    const float* __restrict__ W, _Float16* __restrict__ Wth, _Float16* __restrict__ Wtl)
{
    __shared__ float t[32][33];
    const int n0 = blockIdx.x * 32, k0 = blockIdx.y * 32;
    const int tid = threadIdx.x;
    const int c = tid & 31, r8 = tid >> 5;
#pragma unroll
    for (int p = 0; p < 4; ++p) {
        int r = p * 8 + r8;
        t[r][c] = W[(size_t)(k0 + r) * NC5 + n0 + c];
    }
    __syncthreads();
    const int nl = tid >> 3, k4 = (tid & 7) * 4;
    half4 vh, vl;
#pragma unroll
    for (int i = 0; i < 4; ++i) {
        float v = t[k4 + i][nl];
        _Float16 hh = (_Float16)v;
        vh[i] = hh;
        vl[i] = (_Float16)((v - (float)hh) * 2048.f);
    }
    size_t o = (size_t)(n0 + nl) * 1024 + k0 + k4;
    *(half4*)&Wth[o] = vh;
    *(half4*)&Wtl[o] = vl;
}

// ---------------- word GEMM: leaves -> state slots 0..31 ----------------
__global__ __launch_bounds__(256) void word_gemm64(
    const float* __restrict__ A, const float* __restrict__ W,
    const float* __restrict__ bias,
    _Float16* __restrict__ hi0, _Float16* __restrict__ lo0,
    float* __restrict__ cst, float* __restrict__ out)
{
    const int m0 = blockIdx.x * 64;
    const int n0 = blockIdx.y * 64;
    const int tid = threadIdx.x;
    const int tx = tid & 15, ty = tid >> 4;
    __shared__ float As[16][64];
    __shared__ float Bs[16][64];
    float acc[4][4];
#pragma unroll
    for (int i = 0; i < 4; ++i)
#pragma unroll
        for (int j = 0; j < 4; ++j) acc[i][j] = 0.f;

    for (int kt = 0; kt < ND; kt += 16) {
        {
            int row = tid >> 2, kq = tid & 3;
            float4 v = *(const float4*)(A + (size_t)(m0 + row) * ND + kt + kq * 4);
            As[kq * 4 + 0][row] = v.x;
            As[kq * 4 + 1][row] = v.y;
            As[kq * 4 + 2][row] = v.z;
            As[kq * 4 + 3][row] = v.w;
            int kr = tid >> 4, nq = tid & 15;
            float4 vb = *(const float4*)(W + (size_t)(kt + kr) * 1024 + n0 + nq * 4);
            *(float4*)&Bs[kr][nq * 4] = vb;
        }
        __syncthreads();
#pragma unroll
        for (int kk = 0; kk < 16; ++kk) {
            float a0 = As[kk][ty * 4 + 0], a1 = As[kk][ty * 4 + 1];
            float a2 = As[kk][ty * 4 + 2], a3 = As[kk][ty * 4 + 3];
            float4 bv = *(float4*)&Bs[kk][tx * 4];
            acc[0][0] = fmaf(a0, bv.x, acc[0][0]); acc[0][1] = fmaf(a0, bv.y, acc[0][1]);
            acc[0][2] = fmaf(a0, bv.z, acc[0][2]); acc[0][3] = fmaf(a0, bv.w, acc[0][3]);
            acc[1][0] = fmaf(a1, bv.x, acc[1][0]); acc[1][1] = fmaf(a1, bv.y, acc[1][1]);
            acc[1][2] = fmaf(a1, bv.z, acc[1][2]); acc[1][3] = fmaf(a1, bv.w, acc[1][3]);
            acc[2][0] = fmaf(a2, bv.x, acc[2][0]); acc[2][1] = fmaf(a2, bv.y, acc[2][1]);
            acc[2][2] = fmaf(a2, bv.z, acc[2][2]); acc[2][3] = fmaf(a2, bv.w, acc[2][3]);
            acc[3][0] = fmaf(a3, bv.x, acc[3][0]); acc[3][1] = fmaf(a3, bv.y, acc[3][1]);
            acc[3][2] = fmaf(a3, bv.z, acc[3][2]); acc[3][3] = fmaf(a3, bv.w, acc[3][3]);
        }
        __syncthreads();
    }
    float* nodes = out + 2 * BH;
#pragma unroll
    for (int i = 0; i < 4; ++i) {
        int r = m0 + ty * 4 + i;
        int b = r >> 5, l = r & 31;
#pragma unroll
        for (int jn = 0; jn < 4; ++jn) {
            int n = n0 + tx * 4 + jn;
            float v = acc[i][jn] + bias[n];
            if (n < NHID) {
                size_t si = ((size_t)l * NB + b) * NHID + n;
                _Float16 hh = (_Float16)v;
                hi0[si] = hh;
                lo0[si] = (_Float16)((v - (float)hh) * 2048.f);
                nodes[((size_t)b * 63 + l) * NHID + n] = v;
            } else {
                cst[((size_t)l * NB + b) * NHID + (n - NHID)] = v;
            }
        }
    }
}

// ---------------- persistent kernel: all 31 steps in one dispatch ----------------
// 160 blocks x 256 threads. Block nt: GEMM job = (col tile nt>>1, row-half nt&1);
// update job (blocks 0..31) = batch nt. B panel is preloaded into VGPRs ONCE.
// Per-batch bookkeeping (pidx/hidx/prevk/plog) lives in block b's LDS for the
// whole kernel. Two flag-array grid barriers per step.
__global__ __launch_bounds__(256, 1) void tree_loop(
    _Float16* __restrict__ hHi, _Float16* __restrict__ hLo,
    const _Float16* __restrict__ Wth, const _Float16* __restrict__ Wtl,
    float* __restrict__ graw, const float* __restrict__ bias,
    const float* __restrict__ q, const int* __restrict__ len,
    float* __restrict__ pnh, float* __restrict__ pnc, float* __restrict__ cSt,
    int4* __restrict__ list0, int4* __restrict__ list1,
    int* __restrict__ ireg, float* __restrict__ out)
{
    const int nt = blockIdx.x;
    const int tid = threadIdx.x;
    const int col = nt >> 1;               // 0..79
    const int rh = nt & 1;                 // row-half
    const int kw = tid >> 6;               // wave 0..3 = K chunk
    const int lane = tid & 63;
    const int l5 = lane >> 5, ln = lane & 31;

    int* cnt   = ireg + IR_CNT;
    int* gen   = ireg + IR_GEN;
    int* flags = ireg + IR_FLAG;

    __shared__ float red[4][32][32];       // 16 KB cross-wave reduce
    __shared__ int s_pidx[32], s_hidx[32]; // persistent per-batch bookkeeping
    __shared__ float s_plog[32];           // persistent per-slot logits
    __shared__ int s_k;
    __shared__ int s_prevk;

    // per-batch LDS init (blocks 0..31)
    if (nt < NB) {
        if (tid < 32) { s_pidx[tid] = min(tid, 30); s_hidx[tid] = tid; }
        if (tid == 0) s_prevk = -1;
    }
    const int lenb = (nt < NB) ? len[nt] : 0;
    __syncthreads();

    // B panel preload: 32 cols x 256 K, hi+lo planes -> 128 VGPRs, once.
    const _Float16* bHiP = Wth + (size_t)(col * 32 + ln) * 1024 + (kw << 8) + l5 * 8;
    const _Float16* bLoP = Wtl + (size_t)(col * 32 + ln) * 1024 + (kw << 8) + l5 * 8;
    half8 Bh[16], Bl[16];
#pragma unroll
    for (int ks = 0; ks < 16; ++ks) {
        Bh[ks] = *(const half8*)(bHiP + ks * 16);
        Bl[ks] = *(const half8*)(bLoP + ks * 16);
    }

    int epoch = 0;

    for (int step = 0; step < NSTEPS; ++step) {
        const int p = step & 1;
        const int4* list = p ? list1 : list0;
        int4* lnxt = p ? list0 : list1;
        int* cnt_next = cnt + (1 - p);

        const int count = cnt[p];
        if (nt == 0 && tid == 0) *cnt_next = 0;

        // ---- GEMM phase: raw gates for listed fresh pairs ----
        if (count > 0) {
            const int nmt = (count + 31) >> 5;
            for (int mt = rh; mt < nmt; mt += 2) {
                const int rc = min(mt * 32 + ln, count - 1);
                const int4 d = list[rc];   // {b, slot, left, right}
                const int hs = (kw < 2) ? d.z : d.w;
                const int koff = ((kw & 1) << 8) + l5 * 8;
                const _Float16* aHiP = hHi + ((size_t)hs * NB + d.x) * NHID + koff;
                const _Float16* aLoP = hLo + ((size_t)hs * NB + d.x) * NHID + koff;
                f32x16 acc1 = (f32x16)0.f, acc2 = (f32x16)0.f;
#pragma unroll
                for (int ks = 0; ks < 16; ++ks) {
                    half8 Ah = *(const half8*)(aHiP + ks * 16);
                    half8 Al = *(const half8*)(aLoP + ks * 16);
                    acc1 = __builtin_amdgcn_mfma_f32_32x32x16_f16(Ah, Bh[ks], acc1, 0, 0, 0);
                    acc2 = __builtin_amdgcn_mfma_f32_32x32x16_f16(Ah, Bl[ks], acc2, 0, 0, 0);
                    acc2 = __builtin_amdgcn_mfma_f32_32x32x16_f16(Al, Bh[ks], acc2, 0, 0, 0);
                }
                // cross-wave reduce. C/D: col=lane&31, row=(a&3)+8*(a>>2)+4*(lane>>5)
#pragma unroll
                for (int a = 0; a < 16; ++a) {
                    int row = (a & 3) + 8 * (a >> 2) + 4 * l5;
                    red[kw][row][ln] = acc1[a] + acc2[a] * INV2048;
                }
                __syncthreads();
                {
                    const int row = tid >> 3, c0 = (tid & 7) * 4;
                    if (mt * 32 + row < count) {
                        const int4 dr = list[mt * 32 + row];
                        float4 s;
                        s.x = (red[0][row][c0+0] + red[1][row][c0+0]) + (red[2][row][c0+0] + red[3][row][c0+0]);
                        s.y = (red[0][row][c0+1] + red[1][row][c0+1]) + (red[2][row][c0+1] + red[3][row][c0+1]);
                        s.z = (red[0][row][c0+2] + red[1][row][c0+2]) + (red[2][row][c0+2] + red[3][row][c0+2]);
                        s.w = (red[0][row][c0+3] + red[1][row][c0+3]) + (red[2][row][c0+3] + red[3][row][c0+3]);
                        *(float4*)&graw[((size_t)dr.y * NB + dr.x) * NC5 + col * 32 + c0] = s;
                    }
                }
                __syncthreads();           // red reused next row tile
            }
        }

        grid_barrier(flags, gen, ++epoch);

        // ---- UPDATE phase: blocks 0..31, one batch each ----
        if (nt < NB) {
            const int b = nt;
            const int pk = s_prevk;

            // Phase A: activate fresh pairs — one pair per wave, wave-local reduce
            int nf;
            if (step == 0) nf = 31; else if (pk < 0) nf = 0; else nf = (pk >= 1) ? 2 : 1;
            for (int f = kw; f < nf; f += 4) {
                const int j = (step == 0) ? f : (pk - (nf - 1) + f);
                const int slot = s_pidx[j];
                const int ls = s_hidx[j];
                const int rs = s_hidx[j + 1];
                const float* gr = graw + ((size_t)slot * NB + b) * NC5;
                const float* clp = cSt + ((size_t)ls * NB + b) * NHID;
                const float* crp = cSt + ((size_t)rs * NB + b) * NHID;
                float lpart = 0.f;
#pragma unroll
                for (int i = 0; i < 8; ++i) {
                    const int h = lane + 64 * i;
                    float ig = gr[h]          + bias[h];
                    float fl = gr[512 + h]    + bias[512 + h];
                    float fr = gr[1024 + h]   + bias[1024 + h];
                    float u  = gr[1536 + h]   + bias[1536 + h];
                    float o  = gr[2048 + h]   + bias[2048 + h];
                    float cl = clp[h], cr = crp[h];
                    float c  = cl * sigf(fl + 1.f) + cr * sigf(fr + 1.f) + tanhf(u) * sigf(ig);
                    float hh = sigf(o) * tanhf(c);
                    size_t po = ((size_t)slot * NB + b) * NHID + h;
                    pnh[po] = hh;
                    pnc[po] = c;
                    lpart = fmaf(hh, q[h], lpart);
                }
#pragma unroll
                for (int off = 32; off > 0; off >>= 1) lpart += __shfl_down(lpart, off);
                if (lane == 0) s_plog[slot] = lpart;
            }
            __syncthreads();

            // Phase B: argmax over j < actb (first-index tie-break)
            const int actb = lenb - 1 - step;
            const int merge = actb >= 1;
            if (tid < 64) {
                float v = -1e30f;
                int idx = tid;
                if (tid < actb && tid < 31) v = s_plog[s_pidx[tid]];
#pragma unroll
                for (int off = 32; off > 0; off >>= 1) {
                    float ov = __shfl_down(v, off);
                    int   oi = __shfl_down(idx, off);
                    if (ov > v || (ov == v && oi < idx)) { v = ov; idx = oi; }
                }
                if (tid == 0) s_k = idx;
            }
            __syncthreads();
            const int k = s_k;
            const int last = (step == NSTEPS - 1);

            // Phase C: node output, new-node state write, final hf/cf.
            // (reads only positions <= k of s_pidx/s_hidx, untouched by phase D's shift)
            float* noderow = out + 2 * BH + ((size_t)b * 63 + 32 + step) * NHID;
            if (merge) {
                const int kslot = s_pidx[k];
                const int ns = s_hidx[k];
                for (int h = tid; h < NHID; h += 256) {
                    size_t po = ((size_t)kslot * NB + b) * NHID + h;
                    float x = pnh[po], cc = pnc[po];
                    _Float16 hh = (_Float16)x;
                    size_t so = ((size_t)ns * NB + b) * NHID + h;
                    hHi[so] = hh;
                    hLo[so] = (_Float16)((x - (float)hh) * 2048.f);
                    cSt[so] = cc;
                    noderow[h] = x;
                    if (last) { out[b * NHID + h] = x; out[BH + b * NHID + h] = cc; }
                }
            } else {
                const int s0p = s_pidx[0], s0h = s_hidx[0];
                for (int h = tid; h < NHID; h += 256) {
                    if (!last) {
                        noderow[h] = pnh[((size_t)s0p * NB + b) * NHID + h];
                    } else {
                        size_t so = ((size_t)s0h * NB + b) * NHID + h;
                        float x = (float)hHi[so] + (float)hLo[so] * INV2048;
                        noderow[h] = x;
                        out[b * NHID + h] = x;
                        out[BH + b * NHID + h] = cSt[so];
                    }
                }
            }

            // Phase D: build next list from PRE-shift snapshot, then in-place shift
            if (tid == 0) {
                if (merge) {
                    const int nd = (k >= 1) ? 2 : 1;
                    int base = atomicAdd(cnt_next, nd);
                    if (k >= 1)
                        lnxt[base++] = make_int4(b, s_pidx[k - 1], s_hidx[k - 1], s_hidx[k]);
                    lnxt[base] = make_int4(b, s_pidx[k], s_hidx[k],
                                           (k + 2 <= 31) ? s_hidx[k + 2] : HSLOT_Z);
                    const int recycP = s_pidx[k + 1];      // pre-shift value
                    for (int j2 = k + 1; j2 <= 29; ++j2) s_pidx[j2] = s_pidx[j2 + 1];
                    if (k < 30) s_pidx[30] = recycP;
                    for (int pp = k + 1; pp <= 30; ++pp) s_hidx[pp] = s_hidx[pp + 1];
                    s_hidx[31] = HSLOT_Z;
                    s_prevk = k;
                } else {
                    s_prevk = -1;
                }
            }
        }

        grid_barrier(flags, gen, ++epoch);
    }
}

extern "C" void kernel_launch(void* const* d_in, const int* in_sizes, int n_in,
                              void* d_out, int out_size, void* d_ws, size_t ws_size,
                              hipStream_t stream) {
    const float* inp    = (const float*)d_in[0];
    const int*   length = (const int*)d_in[1];
    const float* W_word = (const float*)d_in[2];
    const float* b_word = (const float*)d_in[3];
    const float* W_comp = (const float*)d_in[4];
    const float* b_comp = (const float*)d_in[5];
    const float* q      = (const float*)d_in[6];
    float* out = (float*)d_out;
    float* ws  = (float*)d_ws;

    float*     graw = ws + OFF_GRAW;
    float*     pnh  = ws + OFF_PNH;
    float*     pnc  = ws + OFF_PNC;
    float*     cSt  = ws + OFF_CST;
    _Float16*  hHi  = (_Float16*)(ws + OFF_HHI);
    _Float16*  hLo  = (_Float16*)(ws + OFF_HLO);
    _Float16*  Wth  = (_Float16*)(ws + OFF_WTH);
    _Float16*  Wtl  = (_Float16*)(ws + OFF_WTL);
    int*       ireg = (int*)(ws + OFF_INT);
    int4*      list0 = (int4*)(ws + OFF_LIST);
    int4*      list1 = list0 + 1024;

    init_kernel<<<34, 256, 0, stream>>>(ireg, list0, hHi, hLo, cSt);
    wsplit_kernel<<<dim3(NC5 / 32, 1024 / 32), 256, 0, stream>>>(W_comp, Wth, Wtl);
    word_gemm64<<<dim3(16, 16), 256, 0, stream>>>(inp, W_word, b_word,
                                                  hHi, hLo, cSt, out);
    tree_loop<<<NBLK, 256, 0, stream>>>(hHi, hLo, Wth, Wtl, graw, b_comp, q, length,
                                        pnh, pnc, cSt, list0, list1, ireg, out);
}

// Round 3
// 782.077 us; speedup vs baseline: 1.3955x; 1.2477x over previous
//
#include <hip/hip_runtime.h>
#include <math.h>

// Problem constants
constexpr int NB = 32, NL = 32, ND = 512, NHID = 512, NSTEPS = 31;
constexpr int NC5 = 2560;          // 5H
constexpr int BH = NB * NHID;      // 16384
constexpr int HSLOT_Z = 32;        // zero slot id (h-space and c-space)
constexpr int NBLK = 160;          // 80 col tiles x 2 row halves; all co-resident

constexpr float INV2048 = 1.f / 2048.f;

typedef _Float16 half8  __attribute__((ext_vector_type(8)));
typedef _Float16 half4  __attribute__((ext_vector_type(4)));
typedef float    f32x16 __attribute__((ext_vector_type(16)));

// ---------------- workspace layout (float offsets) ----------------
// h-state slots are WRITE-ONCE: 0..31 leaves, 32 zero, 33+step new nodes (max 63).
// c-state (cSt) stays recycled (33 slots) because it is strictly block-local.
constexpr size_t OFF_GRAW = 0;                                     // [31][32][2560] f32
constexpr size_t OFF_PNH  = OFF_GRAW + (size_t)31 * 32 * 2560;     // [31][32][512]
constexpr size_t OFF_PNC  = OFF_PNH + (size_t)31 * 32 * 512;
constexpr size_t OFF_CST  = OFF_PNC + (size_t)31 * 32 * 512;       // [33][32][512] f32
constexpr size_t OFF_HHI  = OFF_CST + (size_t)33 * 32 * 512;       // halves [64][32][512]
constexpr size_t OFF_HLO  = OFF_HHI + (size_t)64 * 32 * 512 / 2;
constexpr size_t OFF_WTH  = OFF_HLO + (size_t)64 * 32 * 512 / 2;   // W^T hi [n][k] halves
constexpr size_t OFF_WTL  = OFF_WTH + (size_t)NC5 * 1024 / 2;
constexpr size_t OFF_INT  = OFF_WTL + (size_t)NC5 * 1024 / 2;      // int region (8192 ints)
constexpr size_t OFF_LIST = OFF_INT + 8192;                        // 2 lists x 1024 x int4

// int-region layout
constexpr int IR_CNT  = 0;          // [0],[1] ping-pong counters
constexpr int IR_GEN  = 16;         // barrier generation word
constexpr int IR_FLAG = 32;         // + 32*blk : per-block flags (128B apart)

__device__ __forceinline__ float sigf(float x) { return 1.f / (1.f + expf(-x)); }

// ---- coherent (L2-bypassing) access helpers: relaxed agent-scope atomics ----
__device__ __forceinline__ int ld_sc(const int* p) {
    return __hip_atomic_load(p, __ATOMIC_RELAXED, __HIP_MEMORY_SCOPE_AGENT);
}
__device__ __forceinline__ void st_sc(int* p, int v) {
    __hip_atomic_store(p, v, __ATOMIC_RELAXED, __HIP_MEMORY_SCOPE_AGENT);
}
__device__ __forceinline__ unsigned long long ld_sc64(const void* p) {
    return __hip_atomic_load((const unsigned long long*)p, __ATOMIC_RELAXED,
                             __HIP_MEMORY_SCOPE_AGENT);
}
__device__ __forceinline__ void st_sc64(void* p, unsigned long long v) {
    __hip_atomic_store((unsigned long long*)p, v, __ATOMIC_RELAXED,
                       __HIP_MEMORY_SCOPE_AGENT);
}
__device__ __forceinline__ float ldf_sc(const float* p) {
    int v = __hip_atomic_load((const int*)p, __ATOMIC_RELAXED, __HIP_MEMORY_SCOPE_AGENT);
    return __int_as_float(v);
}
__device__ __forceinline__ unsigned long long packf2(float a, float b) {
    return (unsigned long long)__float_as_uint(a) |
           ((unsigned long long)__float_as_uint(b) << 32);
}

// Fence-free grid barrier. All cross-block payloads use sc1 (L2-bypass)
// accesses, so NO cache maintenance is needed: drain own stores (vmcnt),
// publish flag, poll. Per-XCD L2 contents stay intact across barriers.
__device__ __forceinline__ void grid_barrier(int* flags, int* gen, int target) {
    __syncthreads();                                   // drains each wave's vmcnt
    if (threadIdx.x == 0) {
        asm volatile("s_waitcnt vmcnt(0)" ::: "memory");
        st_sc(&flags[blockIdx.x * 32], target);
    }
    if (blockIdx.x == 0) {
        for (int i = threadIdx.x; i < NBLK; i += 256) {
            while (ld_sc(&flags[i * 32]) < target)
                __builtin_amdgcn_s_sleep(1);
        }
        __syncthreads();
        if (threadIdx.x == 0) st_sc(gen, target);
    }
    if (threadIdx.x == 0) {
        while (ld_sc(gen) < target)
            __builtin_amdgcn_s_sleep(1);
    }
    __syncthreads();
}

// ---------------- init: zero slot, step-0 list, sync/int region ----------------
__global__ __launch_bounds__(256) void init_kernel(
    int* __restrict__ ireg, int4* __restrict__ list0,
    _Float16* __restrict__ hHi, _Float16* __restrict__ hLo, float* __restrict__ cSt)
{
    const int blk = blockIdx.x, tid = threadIdx.x;
    if (blk < 32) {
        if (tid < 31) list0[tid * 32 + blk] = make_int4(blk, tid, tid, tid + 1);
    } else if (blk == 32) {
        const size_t zb = (size_t)HSLOT_Z * NB * NHID;
        for (int i = tid; i < NB * NHID; i += 256) {
            hHi[zb + i] = (_Float16)0.f;
            hLo[zb + i] = (_Float16)0.f;
            cSt[zb + i] = 0.f;
        }
    } else {
        for (int i = tid; i < 8192; i += 256) ireg[i] = 0;
        __syncthreads();
        if (tid == 0) { ireg[IR_CNT] = 992; ireg[IR_CNT + 1] = 0; }
    }
}

// ---------------- W_comp -> transposed split fp16 planes ----------------
__global__ __launch_bounds__(256) void wsplit_kernel(
    const float* __restrict__ W, _Float16* __restrict__ Wth, _Float16* __restrict__ Wtl)
{
    __shared__ float t[32][33];
    const int n0 = blockIdx.x * 32, k0 = blockIdx.y * 32;
    const int tid = threadIdx.x;
    const int c = tid & 31, r8 = tid >> 5;
#pragma unroll
    for (int p = 0; p < 4; ++p) {
        int r = p * 8 + r8;
        t[r][c] = W[(size_t)(k0 + r) * NC5 + n0 + c];
    }
    __syncthreads();
    const int nl = tid >> 3, k4 = (tid & 7) * 4;
    half4 vh, vl;
#pragma unroll
    for (int i = 0; i < 4; ++i) {
        float v = t[k4 + i][nl];
        _Float16 hh = (_Float16)v;
        vh[i] = hh;
        vl[i] = (_Float16)((v - (float)hh) * 2048.f);
    }
    size_t o = (size_t)(n0 + nl) * 1024 + k0 + k4;
    *(half4*)&Wth[o] = vh;
    *(half4*)&Wtl[o] = vl;
}

// ---------------- word GEMM: leaves -> state slots 0..31 ----------------
__global__ __launch_bounds__(256) void word_gemm64(
    const float* __restrict__ A, const float* __restrict__ W,
    const float* __restrict__ bias,
    _Float16* __restrict__ hi0, _Float16* __restrict__ lo0,
    float* __restrict__ cst, float* __restrict__ out)
{
    const int m0 = blockIdx.x * 64;
    const int n0 = blockIdx.y * 64;
    const int tid = threadIdx.x;
    const int tx = tid & 15, ty = tid >> 4;
    __shared__ float As[16][64];
    __shared__ float Bs[16][64];
    float acc[4][4];
#pragma unroll
    for (int i = 0; i < 4; ++i)
#pragma unroll
        for (int j = 0; j < 4; ++j) acc[i][j] = 0.f;

    for (int kt = 0; kt < ND; kt += 16) {
        {
            int row = tid >> 2, kq = tid & 3;
            float4 v = *(const float4*)(A + (size_t)(m0 + row) * ND + kt + kq * 4);
            As[kq * 4 + 0][row] = v.x;
            As[kq * 4 + 1][row] = v.y;
            As[kq * 4 + 2][row] = v.z;
            As[kq * 4 + 3][row] = v.w;
            int kr = tid >> 4, nq = tid & 15;
            float4 vb = *(const float4*)(W + (size_t)(kt + kr) * 1024 + n0 + nq * 4);
            *(float4*)&Bs[kr][nq * 4] = vb;
        }
        __syncthreads();
#pragma unroll
        for (int kk = 0; kk < 16; ++kk) {
            float a0 = As[kk][ty * 4 + 0], a1 = As[kk][ty * 4 + 1];
            float a2 = As[kk][ty * 4 + 2], a3 = As[kk][ty * 4 + 3];
            float4 bv = *(float4*)&Bs[kk][tx * 4];
            acc[0][0] = fmaf(a0, bv.x, acc[0][0]); acc[0][1] = fmaf(a0, bv.y, acc[0][1]);
            acc[0][2] = fmaf(a0, bv.z, acc[0][2]); acc[0][3] = fmaf(a0, bv.w, acc[0][3]);
            acc[1][0] = fmaf(a1, bv.x, acc[1][0]); acc[1][1] = fmaf(a1, bv.y, acc[1][1]);
            acc[1][2] = fmaf(a1, bv.z, acc[1][2]); acc[1][3] = fmaf(a1, bv.w, acc[1][3]);
            acc[2][0] = fmaf(a2, bv.x, acc[2][0]); acc[2][1] = fmaf(a2, bv.y, acc[2][1]);
            acc[2][2] = fmaf(a2, bv.z, acc[2][2]); acc[2][3] = fmaf(a2, bv.w, acc[2][3]);
            acc[3][0] = fmaf(a3, bv.x, acc[3][0]); acc[3][1] = fmaf(a3, bv.y, acc[3][1]);
            acc[3][2] = fmaf(a3, bv.z, acc[3][2]); acc[3][3] = fmaf(a3, bv.w, acc[3][3]);
        }
        __syncthreads();
    }
    float* nodes = out + 2 * BH;
#pragma unroll
    for (int i = 0; i < 4; ++i) {
        int r = m0 + ty * 4 + i;
        int b = r >> 5, l = r & 31;
#pragma unroll
        for (int jn = 0; jn < 4; ++jn) {
            int n = n0 + tx * 4 + jn;
            float v = acc[i][jn] + bias[n];
            if (n < NHID) {
                size_t si = ((size_t)l * NB + b) * NHID + n;
                _Float16 hh = (_Float16)v;
                hi0[si] = hh;
                lo0[si] = (_Float16)((v - (float)hh) * 2048.f);
                nodes[((size_t)b * 63 + l) * NHID + n] = v;
            } else {
                cst[((size_t)l * NB + b) * NHID + (n - NHID)] = v;
            }
        }
    }
}

// ---------------- persistent kernel: all 31 steps, fence-free coherence ----------------
// Cross-XCD payloads (graw, fresh hHi/hLo, lists, cnt, flags) use sc1 atomics.
// Everything else (old A states = write-once slots, B panels in VGPRs, bias, q,
// cSt/pnh/pnc block-local) uses normal cached access and stays L2-hot.
__global__ __launch_bounds__(256, 1) void tree_loop(
    _Float16* __restrict__ hHi, _Float16* __restrict__ hLo,
    const _Float16* __restrict__ Wth, const _Float16* __restrict__ Wtl,
    float* __restrict__ graw, const float* __restrict__ bias,
    const float* __restrict__ q, const int* __restrict__ len,
    float* __restrict__ pnh, float* __restrict__ pnc, float* __restrict__ cSt,
    int4* __restrict__ list0, int4* __restrict__ list1,
    int* __restrict__ ireg, float* __restrict__ out)
{
    const int nt = blockIdx.x;
    const int tid = threadIdx.x;
    const int col = nt >> 1;               // 0..79
    const int rh = nt & 1;                 // row-half
    const int kw = tid >> 6;               // wave 0..3 = K chunk
    const int lane = tid & 63;
    const int l5 = lane >> 5, ln = lane & 31;

    int* cnt   = ireg + IR_CNT;
    int* gen   = ireg + IR_GEN;
    int* flags = ireg + IR_FLAG;

    __shared__ float red[4][32][32];       // 16 KB cross-wave reduce
    __shared__ int s_pidx[32];             // pair-slot ids (graw/pnh space, recycled)
    __shared__ int s_hidx[32];             // h-state slot ids (WRITE-ONCE space 0..63)
    __shared__ int s_cidx[32];             // c-state slot ids (recycled 0..32)
    __shared__ float s_plog[32];           // per-pair-slot logits
    __shared__ int s_k;
    __shared__ int s_prevk;

    if (nt < NB) {
        if (tid < 32) {
            s_pidx[tid] = min(tid, 30);
            s_hidx[tid] = tid;
            s_cidx[tid] = tid;
        }
        if (tid == 0) s_prevk = -1;
    }
    const int lenb = (nt < NB) ? len[nt] : 0;
    __syncthreads();

    // B panel preload: 32 cols x 256 K, hi+lo planes -> 128 VGPRs, once.
    const _Float16* bHiP = Wth + (size_t)(col * 32 + ln) * 1024 + (kw << 8) + l5 * 8;
    const _Float16* bLoP = Wtl + (size_t)(col * 32 + ln) * 1024 + (kw << 8) + l5 * 8;
    half8 Bh[16], Bl[16];
#pragma unroll
    for (int ks = 0; ks < 16; ++ks) {
        Bh[ks] = *(const half8*)(bHiP + ks * 16);
        Bl[ks] = *(const half8*)(bLoP + ks * 16);
    }

    int epoch = 0;

    for (int step = 0; step < NSTEPS; ++step) {
        const int p = step & 1;
        const int4* list = p ? list1 : list0;
        int4* lnxt = p ? list0 : list1;
        int* cnt_next = cnt + (1 - p);

        const int count = ld_sc(&cnt[p]);
        if (nt == 0 && tid == 0) st_sc(cnt_next, 0);

        // ---- GEMM phase: raw gates for listed fresh pairs ----
        if (count > 0) {
            const int nmt = (count + 31) >> 5;
            for (int mt = rh; mt < nmt; mt += 2) {
                const int rc = min(mt * 32 + ln, count - 1);
                unsigned long long w0 = ld_sc64(&list[rc]);
                unsigned long long w1 = ld_sc64((const char*)&list[rc] + 8);
                const int db = (int)w0;                 // batch
                const int dz = (int)w1, dw = (int)(w1 >> 32);  // left/right h-slots
                const int hs = (kw < 2) ? dz : dw;
                const int koff = ((kw & 1) << 8) + l5 * 8;
                // normal cached loads: h-slots are write-once, never stale
                const _Float16* aHiP = hHi + ((size_t)hs * NB + db) * NHID + koff;
                const _Float16* aLoP = hLo + ((size_t)hs * NB + db) * NHID + koff;
                f32x16 acc1 = (f32x16)0.f, acc2 = (f32x16)0.f;
#pragma unroll
                for (int ks = 0; ks < 16; ++ks) {
                    half8 Ah = *(const half8*)(aHiP + ks * 16);
                    half8 Al = *(const half8*)(aLoP + ks * 16);
                    acc1 = __builtin_amdgcn_mfma_f32_32x32x16_f16(Ah, Bh[ks], acc1, 0, 0, 0);
                    acc2 = __builtin_amdgcn_mfma_f32_32x32x16_f16(Ah, Bl[ks], acc2, 0, 0, 0);
                    acc2 = __builtin_amdgcn_mfma_f32_32x32x16_f16(Al, Bh[ks], acc2, 0, 0, 0);
                }
                // cross-wave reduce. C/D: col=lane&31, row=(a&3)+8*(a>>2)+4*(lane>>5)
#pragma unroll
                for (int a = 0; a < 16; ++a) {
                    int row = (a & 3) + 8 * (a >> 2) + 4 * l5;
                    red[kw][row][ln] = acc1[a] + acc2[a] * INV2048;
                }
                __syncthreads();
                {
                    const int row = tid >> 3, c0 = (tid & 7) * 4;
                    if (mt * 32 + row < count) {
                        unsigned long long rw0 = ld_sc64(&list[mt * 32 + row]);
                        const int rb = (int)rw0, rslot = (int)(rw0 >> 32);
                        float4 s;
                        s.x = (red[0][row][c0+0] + red[1][row][c0+0]) + (red[2][row][c0+0] + red[3][row][c0+0]);
                        s.y = (red[0][row][c0+1] + red[1][row][c0+1]) + (red[2][row][c0+1] + red[3][row][c0+1]);
                        s.z = (red[0][row][c0+2] + red[1][row][c0+2]) + (red[2][row][c0+2] + red[3][row][c0+2]);
                        s.w = (red[0][row][c0+3] + red[1][row][c0+3]) + (red[2][row][c0+3] + red[3][row][c0+3]);
                        float* gp = &graw[((size_t)rslot * NB + rb) * NC5 + col * 32 + c0];
                        st_sc64(gp,     packf2(s.x, s.y));   // sc1: cross-XCD payload
                        st_sc64(gp + 2, packf2(s.z, s.w));
                    }
                }
                __syncthreads();           // red reused next row tile
            }
        }

        grid_barrier(flags, gen, ++epoch);

        // ---- UPDATE phase: blocks 0..31, one batch each ----
        if (nt < NB) {
            const int b = nt;
            const int pk = s_prevk;

            // Phase A: activate fresh pairs — one pair per wave
            int nf;
            if (step == 0) nf = 31; else if (pk < 0) nf = 0; else nf = (pk >= 1) ? 2 : 1;
            for (int f = kw; f < nf; f += 4) {
                const int j = (step == 0) ? f : (pk - (nf - 1) + f);
                const int slot = s_pidx[j];
                const int lc = s_cidx[j];
                const int rc2 = s_cidx[j + 1];
                const float* gr = graw + ((size_t)slot * NB + b) * NC5;
                const float* clp = cSt + ((size_t)lc * NB + b) * NHID;   // block-local, cached
                const float* crp = cSt + ((size_t)rc2 * NB + b) * NHID;
                float lpart = 0.f;
#pragma unroll
                for (int i = 0; i < 8; ++i) {
                    const int h = lane + 64 * i;
                    float ig = ldf_sc(gr + h)          + bias[h];
                    float fl = ldf_sc(gr + 512 + h)    + bias[512 + h];
                    float fr = ldf_sc(gr + 1024 + h)   + bias[1024 + h];
                    float u  = ldf_sc(gr + 1536 + h)   + bias[1536 + h];
                    float o  = ldf_sc(gr + 2048 + h)   + bias[2048 + h];
                    float cl = clp[h], cr = crp[h];
                    float c  = cl * sigf(fl + 1.f) + cr * sigf(fr + 1.f) + tanhf(u) * sigf(ig);
                    float hh = sigf(o) * tanhf(c);
                    size_t po = ((size_t)slot * NB + b) * NHID + h;
                    pnh[po] = hh;                       // block-local, cached
                    pnc[po] = c;
                    lpart = fmaf(hh, q[h], lpart);
                }
#pragma unroll
                for (int off = 32; off > 0; off >>= 1) lpart += __shfl_down(lpart, off);
                if (lane == 0) s_plog[slot] = lpart;
            }
            __syncthreads();

            // Phase B: argmax over j < actb (first-index tie-break)
            const int actb = lenb - 1 - step;
            const int merge = actb >= 1;
            if (tid < 64) {
                float v = -1e30f;
                int idx = tid;
                if (tid < actb && tid < 31) v = s_plog[s_pidx[tid]];
#pragma unroll
                for (int off = 32; off > 0; off >>= 1) {
                    float ov = __shfl_down(v, off);
                    int   oi = __shfl_down(idx, off);
                    if (ov > v || (ov == v && oi < idx)) { v = ov; idx = oi; }
                }
                if (tid == 0) s_k = idx;
            }
            __syncthreads();
            const int k = s_k;
            const int last = (step == NSTEPS - 1);
            const int NSLOT = 33 + step;               // fresh write-once h-slot

            // Phase C: node output, new-node state write, final hf/cf
            float* noderow = out + 2 * BH + ((size_t)b * 63 + 32 + step) * NHID;
            if (merge) {
                const int kslot = s_pidx[k];
                const int csl = s_cidx[k];             // recycled c-slot
                if (tid < 128) {
                    const int h0 = tid * 4;
                    const size_t pb = ((size_t)kslot * NB + b) * NHID + h0;
                    float4 x4 = *(const float4*)&pnh[pb];
                    float4 c4 = *(const float4*)&pnc[pb];
                    half4 hv, lv;
#pragma unroll
                    for (int i = 0; i < 4; ++i) {
                        float x = (&x4.x)[i];
                        _Float16 hh = (_Float16)x;
                        hv[i] = hh;
                        lv[i] = (_Float16)((x - (float)hh) * 2048.f);
                    }
                    const size_t so = ((size_t)NSLOT * NB + b) * NHID + h0;
                    st_sc64(&hHi[so], __builtin_bit_cast(unsigned long long, hv));
                    st_sc64(&hLo[so], __builtin_bit_cast(unsigned long long, lv));
                    *(float4*)&cSt[((size_t)csl * NB + b) * NHID + h0] = c4;
                    *(float4*)&noderow[h0] = x4;
                    if (last) {
                        *(float4*)&out[b * NHID + h0] = x4;
                        *(float4*)&out[BH + b * NHID + h0] = c4;
                    }
                }
            } else {
                const int s0p = s_pidx[0], s0h = s_hidx[0], s0c = s_cidx[0];
                if (tid < 128) {
                    const int h0 = tid * 4;
                    if (!last) {
                        *(float4*)&noderow[h0] =
                            *(const float4*)&pnh[((size_t)s0p * NB + b) * NHID + h0];
                    } else {
                        const size_t so = ((size_t)s0h * NB + b) * NHID + h0;
                        half4 hv = __builtin_bit_cast(half4, ld_sc64(&hHi[so]));
                        half4 lv = __builtin_bit_cast(half4, ld_sc64(&hLo[so]));
                        float4 x4;
#pragma unroll
                        for (int i = 0; i < 4; ++i)
                            (&x4.x)[i] = (float)hv[i] + (float)lv[i] * INV2048;
                        *(float4*)&noderow[h0] = x4;
                        *(float4*)&out[b * NHID + h0] = x4;
                        *(float4*)&out[BH + b * NHID + h0] =
                            *(const float4*)&cSt[((size_t)s0c * NB + b) * NHID + h0];
                    }
                }
            }

            // Phase D: build next list (sc1), then shift LDS bookkeeping
            if (tid == 0) {
                if (merge) {
                    const int nd = (k >= 1) ? 2 : 1;
                    int base = atomicAdd(cnt_next, nd);
                    if (k >= 1) {
                        int4* e = &lnxt[base++];
                        st_sc64(e, (unsigned long long)(unsigned)b |
                                   ((unsigned long long)(unsigned)s_pidx[k - 1] << 32));
                        st_sc64((char*)e + 8, (unsigned long long)(unsigned)s_hidx[k - 1] |
                                   ((unsigned long long)(unsigned)NSLOT << 32));
                    }
                    {
                        int rn = (k + 2 <= 31) ? s_hidx[k + 2] : HSLOT_Z;
                        int4* e = &lnxt[base];
                        st_sc64(e, (unsigned long long)(unsigned)b |
                                   ((unsigned long long)(unsigned)s_pidx[k] << 32));
                        st_sc64((char*)e + 8, (unsigned long long)(unsigned)NSLOT |
                                   ((unsigned long long)(unsigned)rn << 32));
                    }
                    const int recycP = s_pidx[k + 1];  // pre-shift value
                    for (int j2 = k + 1; j2 <= 29; ++j2) s_pidx[j2] = s_pidx[j2 + 1];
                    if (k < 30) s_pidx[30] = recycP;
                    s_hidx[k] = NSLOT;
                    for (int pp = k + 1; pp <= 30; ++pp) s_hidx[pp] = s_hidx[pp + 1];
                    s_hidx[31] = HSLOT_Z;
                    for (int pp = k + 1; pp <= 30; ++pp) s_cidx[pp] = s_cidx[pp + 1];
                    s_cidx[31] = HSLOT_Z;
                    s_prevk = k;
                } else {
                    s_prevk = -1;
                }
            }
        }

        if (step != NSTEPS - 1) grid_barrier(flags, gen, ++epoch);
    }
}

extern "C" void kernel_launch(void* const* d_in, const int* in_sizes, int n_in,
                              void* d_out, int out_size, void* d_ws, size_t ws_size,
                              hipStream_t stream) {
    const float* inp    = (const float*)d_in[0];
    const int*   length = (const int*)d_in[1];
    const float* W_word = (const float*)d_in[2];
    const float* b_word = (const float*)d_in[3];
    const float* W_comp = (const float*)d_in[4];
    const float* b_comp = (const float*)d_in[5];
    const float* q      = (const float*)d_in[6];
    float* out = (float*)d_out;
    float* ws  = (float*)d_ws;

    float*     graw = ws + OFF_GRAW;
    float*     pnh  = ws + OFF_PNH;
    float*     pnc  = ws + OFF_PNC;
    float*     cSt  = ws + OFF_CST;
    _Float16*  hHi  = (_Float16*)(ws + OFF_HHI);
    _Float16*  hLo  = (_Float16*)(ws + OFF_HLO);
    _Float16*  Wth  = (_Float16*)(ws + OFF_WTH);
    _Float16*  Wtl  = (_Float16*)(ws + OFF_WTL);
    int*       ireg = (int*)(ws + OFF_INT);
    int4*      list0 = (int4*)(ws + OFF_LIST);
    int4*      list1 = list0 + 1024;

    init_kernel<<<34, 256, 0, stream>>>(ireg, list0, hHi, hLo, cSt);
    wsplit_kernel<<<dim3(NC5 / 32, 1024 / 32), 256, 0, stream>>>(W_comp, Wth, Wtl);
    word_gemm64<<<dim3(16, 16), 256, 0, stream>>>(inp, W_word, b_word,
                                                  hHi, hLo, cSt, out);
    tree_loop<<<NBLK, 256, 0, stream>>>(hHi, hLo, Wth, Wtl, graw, b_comp, q, length,
                                        pnh, pnc, cSt, list0, list1, ireg, out);
}

// Round 4
// 766.041 us; speedup vs baseline: 1.4248x; 1.0209x over previous
//
#include <hip/hip_runtime.h>
#include <math.h>

// Problem constants
constexpr int NB = 32, NL = 32, ND = 512, NHID = 512, NSTEPS = 31;
constexpr int NC5 = 2560;          // 5H
constexpr int BH = NB * NHID;      // 16384
constexpr int HSLOT_Z = 32;        // zero slot id
constexpr int NBLK = 160;          // 80 GEMM + 32 update + 48 step0-only
constexpr int NGEMM = 80;

constexpr float INV2048 = 1.f / 2048.f;

typedef _Float16 half8  __attribute__((ext_vector_type(8)));
typedef _Float16 half4  __attribute__((ext_vector_type(4)));
typedef float    f32x16 __attribute__((ext_vector_type(16)));
typedef unsigned long long u64;

// ---------------- workspace layout (float offsets) ----------------
// h-state slots WRITE-ONCE: 0..31 leaves, 32 zero, 33+step fresh nodes (<=62).
// graw has a dummy slot 31 for padded (non-merging) pairs.
constexpr size_t OFF_GRAW = 0;                                     // [32][32][2560] f32
constexpr size_t OFF_PNH  = OFF_GRAW + (size_t)32 * 32 * 2560;     // [31][32][512]
constexpr size_t OFF_PNC  = OFF_PNH + (size_t)31 * 32 * 512;
constexpr size_t OFF_CST  = OFF_PNC + (size_t)31 * 32 * 512;       // [33][32][512]
constexpr size_t OFF_HHI  = OFF_CST + (size_t)33 * 32 * 512;       // halves [64][32][512]
constexpr size_t OFF_HLO  = OFF_HHI + (size_t)64 * 32 * 512 / 2;
constexpr size_t OFF_WTH  = OFF_HLO + (size_t)64 * 32 * 512 / 2;   // W^T hi [n][k]
constexpr size_t OFF_WTL  = OFF_WTH + (size_t)NC5 * 1024 / 2;
constexpr size_t OFF_INT  = OFF_WTL + (size_t)NC5 * 1024 / 2;      // 8192 ints
constexpr size_t OFF_LIST = OFF_INT + 8192;                        // 992 u64 entries

// int-region: gd stripes at [0],[32],[64],[96] (cumulative GEMM arrivals)
__device__ __forceinline__ float sigf(float x) { return 1.f / (1.f + expf(-x)); }

// ---- coherent (L2-bypassing) helpers: relaxed agent-scope atomics ----
__device__ __forceinline__ int ld_sc(const int* p) {
    return __hip_atomic_load(p, __ATOMIC_RELAXED, __HIP_MEMORY_SCOPE_AGENT);
}
__device__ __forceinline__ u64 ld_sc64(const void* p) {
    return __hip_atomic_load((const u64*)p, __ATOMIC_RELAXED, __HIP_MEMORY_SCOPE_AGENT);
}
__device__ __forceinline__ void st_sc64(void* p, u64 v) {
    __hip_atomic_store((u64*)p, v, __ATOMIC_RELAXED, __HIP_MEMORY_SCOPE_AGENT);
}
__device__ __forceinline__ u64 packf2(float a, float b) {
    return (u64)__float_as_uint(a) | ((u64)__float_as_uint(b) << 32);
}
__device__ __forceinline__ float2 uf2(u64 v) {
    float2 r;
    r.x = __uint_as_float((unsigned)v);
    r.y = __uint_as_float((unsigned)(v >> 32));
    return r;
}

// entry pack: bits0-4 batch, 5-9 pair-slot (31=dummy), 10-15 left h-slot,
// 16-21 right h-slot; high 32 = step stamp (monotonic within a dispatch).
__device__ __forceinline__ unsigned pack_e(int b, int slot, int l, int r) {
    return (unsigned)b | ((unsigned)slot << 5) | ((unsigned)l << 10) | ((unsigned)r << 16);
}

// ---------------- init: zero slot, step-0 entries, counters ----------------
__global__ __launch_bounds__(256) void init_kernel(
    int* __restrict__ ireg, u64* __restrict__ elist,
    _Float16* __restrict__ hHi, _Float16* __restrict__ hLo, float* __restrict__ cSt)
{
    const int blk = blockIdx.x, tid = threadIdx.x;
    if (blk < 32) {
        if (tid < 31) {
            unsigned e = (unsigned)blk | ((unsigned)tid << 5) |
                         ((unsigned)tid << 10) | ((unsigned)(tid + 1) << 16);
            elist[tid * 32 + blk] = (u64)e;      // stamp 0
        }
    } else if (blk == 32) {
        const size_t zb = (size_t)HSLOT_Z * NB * NHID;
        for (int i = tid; i < NB * NHID; i += 256) {
            hHi[zb + i] = (_Float16)0.f;
            hLo[zb + i] = (_Float16)0.f;
            cSt[zb + i] = 0.f;
        }
    } else {
        for (int i = tid; i < 8192; i += 256) ireg[i] = 0;
    }
}

// ---------------- W_comp -> transposed split fp16 planes ----------------
__global__ __launch_bounds__(256) void wsplit_kernel(
    const float* __restrict__ W, _Float16* __restrict__ Wth, _Float16* __restrict__ Wtl)
{
    __shared__ float t[32][33];
    const int n0 = blockIdx.x * 32, k0 = blockIdx.y * 32;
    const int tid = threadIdx.x;
    const int c = tid & 31, r8 = tid >> 5;
#pragma unroll
    for (int p = 0; p < 4; ++p) {
        int r = p * 8 + r8;
        t[r][c] = W[(size_t)(k0 + r) * NC5 + n0 + c];
    }
    __syncthreads();
    const int nl = tid >> 3, k4 = (tid & 7) * 4;
    half4 vh, vl;
#pragma unroll
    for (int i = 0; i < 4; ++i) {
        float v = t[k4 + i][nl];
        _Float16 hh = (_Float16)v;
        vh[i] = hh;
        vl[i] = (_Float16)((v - (float)hh) * 2048.f);
    }
    size_t o = (size_t)(n0 + nl) * 1024 + k0 + k4;
    *(half4*)&Wth[o] = vh;
    *(half4*)&Wtl[o] = vl;
}

// ---------------- word GEMM: leaves -> state slots 0..31 ----------------
__global__ __launch_bounds__(256) void word_gemm64(
    const float* __restrict__ A, const float* __restrict__ W,
    const float* __restrict__ bias,
    _Float16* __restrict__ hi0, _Float16* __restrict__ lo0,
    float* __restrict__ cst, float* __restrict__ out)
{
    const int m0 = blockIdx.x * 64;
    const int n0 = blockIdx.y * 64;
    const int tid = threadIdx.x;
    const int tx = tid & 15, ty = tid >> 4;
    __shared__ float As[16][64];
    __shared__ float Bs[16][64];
    float acc[4][4];
#pragma unroll
    for (int i = 0; i < 4; ++i)
#pragma unroll
        for (int j = 0; j < 4; ++j) acc[i][j] = 0.f;

    for (int kt = 0; kt < ND; kt += 16) {
        {
            int row = tid >> 2, kq = tid & 3;
            float4 v = *(const float4*)(A + (size_t)(m0 + row) * ND + kt + kq * 4);
            As[kq * 4 + 0][row] = v.x;
            As[kq * 4 + 1][row] = v.y;
            As[kq * 4 + 2][row] = v.z;
            As[kq * 4 + 3][row] = v.w;
            int kr = tid >> 4, nq = tid & 15;
            float4 vb = *(const float4*)(W + (size_t)(kt + kr) * 1024 + n0 + nq * 4);
            *(float4*)&Bs[kr][nq * 4] = vb;
        }
        __syncthreads();
#pragma unroll
        for (int kk = 0; kk < 16; ++kk) {
            float a0 = As[kk][ty * 4 + 0], a1 = As[kk][ty * 4 + 1];
            float a2 = As[kk][ty * 4 + 2], a3 = As[kk][ty * 4 + 3];
            float4 bv = *(float4*)&Bs[kk][tx * 4];
            acc[0][0] = fmaf(a0, bv.x, acc[0][0]); acc[0][1] = fmaf(a0, bv.y, acc[0][1]);
            acc[0][2] = fmaf(a0, bv.z, acc[0][2]); acc[0][3] = fmaf(a0, bv.w, acc[0][3]);
            acc[1][0] = fmaf(a1, bv.x, acc[1][0]); acc[1][1] = fmaf(a1, bv.y, acc[1][1]);
            acc[1][2] = fmaf(a1, bv.z, acc[1][2]); acc[1][3] = fmaf(a1, bv.w, acc[1][3]);
            acc[2][0] = fmaf(a2, bv.x, acc[2][0]); acc[2][1] = fmaf(a2, bv.y, acc[2][1]);
            acc[2][2] = fmaf(a2, bv.z, acc[2][2]); acc[2][3] = fmaf(a2, bv.w, acc[2][3]);
            acc[3][0] = fmaf(a3, bv.x, acc[3][0]); acc[3][1] = fmaf(a3, bv.y, acc[3][1]);
            acc[3][2] = fmaf(a3, bv.z, acc[3][2]); acc[3][3] = fmaf(a3, bv.w, acc[3][3]);
        }
        __syncthreads();
    }
    float* nodes = out + 2 * BH;
#pragma unroll
    for (int i = 0; i < 4; ++i) {
        int r = m0 + ty * 4 + i;
        int b = r >> 5, l = r & 31;
#pragma unroll
        for (int jn = 0; jn < 4; ++jn) {
            int n = n0 + tx * 4 + jn;
            float v = acc[i][jn] + bias[n];
            if (n < NHID) {
                size_t si = ((size_t)l * NB + b) * NHID + n;
                _Float16 hh = (_Float16)v;
                hi0[si] = hh;
                lo0[si] = (_Float16)((v - (float)hh) * 2048.f);
                nodes[((size_t)b * 63 + l) * NHID + n] = v;
            } else {
                cst[((size_t)l * NB + b) * NHID + (n - NHID)] = v;
            }
        }
    }
}

// ---------------- persistent kernel: single-hop pipelined steps ----------------
// Blocks 0..79: GEMM (col nt, B panel in VGPRs). Blocks 80..111: update (batch
// nt-80). Blocks 112..159: step-0 GEMM only. Sync: update->GEMM via stamped
// 64-bit list entries (polled directly); GEMM->update via 4 striped cumulative
// counters. Fixed 64-row lists (dummy slot 31, zero operands). No fences.
__global__ __launch_bounds__(256, 1) void tree_loop(
    _Float16* __restrict__ hHi, _Float16* __restrict__ hLo,
    const _Float16* __restrict__ Wth, const _Float16* __restrict__ Wtl,
    float* __restrict__ graw, const float* __restrict__ bias,
    const float* __restrict__ q, const int* __restrict__ len,
    float* __restrict__ pnh, float* __restrict__ pnc, float* __restrict__ cSt,
    u64* __restrict__ elist, int* __restrict__ ireg, float* __restrict__ out)
{
    const int nt = blockIdx.x;
    const int tid = threadIdx.x;
    const int col = nt % NGEMM;            // col tile for GEMM work
    const int kw = tid >> 6;               // wave 0..3 = K chunk
    const int lane = tid & 63;
    const int l5 = lane >> 5, ln = lane & 31;

    int* gd = ireg;                        // 4 striped cumulative counters

    __shared__ float red[4][32][32];       // 16 KB cross-wave reduce
    __shared__ unsigned s_entry[64];
    __shared__ int s_pidx[32], s_hidx[32], s_cidx[32];
    __shared__ float s_plog[32];
    __shared__ int s_k;
    __shared__ int s_prevk;

    // B panel preload: 32 cols x 256 K per wave, hi+lo -> 128 VGPRs, once.
    const _Float16* bHiP = Wth + (size_t)(col * 32 + ln) * 1024 + (kw << 8) + l5 * 8;
    const _Float16* bLoP = Wtl + (size_t)(col * 32 + ln) * 1024 + (kw << 8) + l5 * 8;
    half8 Bh[16], Bl[16];
#pragma unroll
    for (int ks = 0; ks < 16; ++ks) {
        Bh[ks] = *(const half8*)(bHiP + ks * 16);
        Bl[ks] = *(const half8*)(bLoP + ks * 16);
    }

    // one 32-row GEMM tile: entries come from se[0..31]
    auto gemm_tile = [&](const unsigned* se) {
        {
            const unsigned e = se[ln];
            const int db = e & 31;
            const int lsl = (e >> 10) & 63, rsl = (e >> 16) & 63;
            const int hs = (kw < 2) ? lsl : rsl;
            const int koff = ((kw & 1) << 8) + l5 * 8;
            const _Float16* aHiP = hHi + ((size_t)hs * NB + db) * NHID + koff;
            const _Float16* aLoP = hLo + ((size_t)hs * NB + db) * NHID + koff;
            f32x16 acc1 = (f32x16)0.f, acc2 = (f32x16)0.f;
#pragma unroll
            for (int ks = 0; ks < 16; ++ks) {
                half8 Ah = *(const half8*)(aHiP + ks * 16);
                half8 Al = *(const half8*)(aLoP + ks * 16);
                acc1 = __builtin_amdgcn_mfma_f32_32x32x16_f16(Ah, Bh[ks], acc1, 0, 0, 0);
                acc2 = __builtin_amdgcn_mfma_f32_32x32x16_f16(Ah, Bl[ks], acc2, 0, 0, 0);
                acc2 = __builtin_amdgcn_mfma_f32_32x32x16_f16(Al, Bh[ks], acc2, 0, 0, 0);
            }
            // C/D: col=lane&31, row=(a&3)+8*(a>>2)+4*(lane>>5)
#pragma unroll
            for (int a = 0; a < 16; ++a) {
                int row = (a & 3) + 8 * (a >> 2) + 4 * l5;
                red[kw][row][ln] = acc1[a] + acc2[a] * INV2048;
            }
        }
        __syncthreads();
        {
            const int row = tid >> 3, c0 = (tid & 7) * 4;
            const unsigned er = se[row];
            const int rb = er & 31, rslot = (er >> 5) & 31;
            float4 s;
            s.x = (red[0][row][c0+0] + red[1][row][c0+0]) + (red[2][row][c0+0] + red[3][row][c0+0]);
            s.y = (red[0][row][c0+1] + red[1][row][c0+1]) + (red[2][row][c0+1] + red[3][row][c0+1]);
            s.z = (red[0][row][c0+2] + red[1][row][c0+2]) + (red[2][row][c0+2] + red[3][row][c0+2]);
            s.w = (red[0][row][c0+3] + red[1][row][c0+3]) + (red[2][row][c0+3] + red[3][row][c0+3]);
            float* gp = &graw[((size_t)rslot * NB + rb) * NC5 + col * 32 + c0];
            st_sc64(gp,     packf2(s.x, s.y));
            st_sc64(gp + 2, packf2(s.z, s.w));
        }
        __syncthreads();
    };

    // ---- step 0: all 160 blocks GEMM (31 tiles, split by parity) ----
    __syncthreads();
    {
        const int par = nt / NGEMM;        // 0 or 1
        for (int mt = par; mt < 31; mt += 2) {
            if (tid < 32) s_entry[tid] = (unsigned)ld_sc64(&elist[mt * 32 + tid]);
            __syncthreads();
            gemm_tile(s_entry);
        }
        if (tid == 0) {
            asm volatile("s_waitcnt vmcnt(0)" ::: "memory");
            __hip_atomic_fetch_add(&gd[(nt & 3) * 32], 1, __ATOMIC_RELAXED,
                                   __HIP_MEMORY_SCOPE_AGENT);
        }
    }
    if (nt >= 112) return;

    if (nt < NGEMM) {
        // ---- GEMM role: steps 1..30 ----
        for (int step = 1; step < NSTEPS; ++step) {
            if (tid < 64) {
                u64 e;
                while ((int)((e = ld_sc64(&elist[tid])) >> 32) < step)
                    __builtin_amdgcn_s_sleep(1);
                s_entry[tid] = (unsigned)e;
            }
            __syncthreads();
            gemm_tile(s_entry);
            gemm_tile(s_entry + 32);
            if (tid == 0) {
                asm volatile("s_waitcnt vmcnt(0)" ::: "memory");
                __hip_atomic_fetch_add(&gd[(nt & 3) * 32], 1, __ATOMIC_RELAXED,
                                       __HIP_MEMORY_SCOPE_AGENT);
            }
        }
        return;
    }

    // ---- UPDATE role: batch b = nt - 80 ----
    {
        const int b = nt - NGEMM;
        const int lenb = len[b];
        if (tid < 32) { s_pidx[tid] = min(tid, 30); s_hidx[tid] = tid; s_cidx[tid] = tid; }
        if (tid == 0) s_prevk = -1;
        __syncthreads();

        for (int step = 0; step < NSTEPS; ++step) {
            // wait for all GEMM arrivals of this step (4 striped counters)
            if (tid < 4) {
                const int tgt = 40 + 20 * step;
                while (ld_sc(&gd[tid * 32]) < tgt) __builtin_amdgcn_s_sleep(1);
            }
            __syncthreads();

            const int pk = s_prevk;
            int nf;
            if (step == 0) nf = 31; else if (pk < 0) nf = 0; else nf = (pk >= 1) ? 2 : 1;
            // Phase A: one fresh pair per wave
            for (int f = kw; f < nf; f += 4) {
                const int j = (step == 0) ? f : (pk - (nf - 1) + f);
                const int slot = s_pidx[j];
                const int lc = s_cidx[j], rc2 = s_cidx[j + 1];
                const float* gr  = graw + ((size_t)slot * NB + b) * NC5;
                const float* clp = cSt + ((size_t)lc * NB + b) * NHID;
                const float* crp = cSt + ((size_t)rc2 * NB + b) * NHID;
                float lpart = 0.f;
#pragma unroll
                for (int i = 0; i < 4; ++i) {
                    const int h = 2 * lane + 128 * i;
                    float2 g0 = uf2(ld_sc64(gr + h));
                    float2 g1 = uf2(ld_sc64(gr + 512 + h));
                    float2 g2 = uf2(ld_sc64(gr + 1024 + h));
                    float2 g3 = uf2(ld_sc64(gr + 1536 + h));
                    float2 g4 = uf2(ld_sc64(gr + 2048 + h));
                    const float2 b0 = *(const float2*)(bias + h);
                    const float2 b1 = *(const float2*)(bias + 512 + h);
                    const float2 b2 = *(const float2*)(bias + 1024 + h);
                    const float2 b3 = *(const float2*)(bias + 1536 + h);
                    const float2 b4 = *(const float2*)(bias + 2048 + h);
                    const float2 cl2 = *(const float2*)(clp + h);
                    const float2 cr2 = *(const float2*)(crp + h);
                    const float2 q2  = *(const float2*)(q + h);
                    float2 hv, cv;
                    {
                        float c = cl2.x * sigf(g1.x + b1.x + 1.f) + cr2.x * sigf(g2.x + b2.x + 1.f)
                                + tanhf(g3.x + b3.x) * sigf(g0.x + b0.x);
                        float hh = sigf(g4.x + b4.x) * tanhf(c);
                        cv.x = c; hv.x = hh;
                    }
                    {
                        float c = cl2.y * sigf(g1.y + b1.y + 1.f) + cr2.y * sigf(g2.y + b2.y + 1.f)
                                + tanhf(g3.y + b3.y) * sigf(g0.y + b0.y);
                        float hh = sigf(g4.y + b4.y) * tanhf(c);
                        cv.y = c; hv.y = hh;
                    }
                    const size_t po = ((size_t)slot * NB + b) * NHID + h;
                    *(float2*)(pnh + po) = hv;
                    *(float2*)(pnc + po) = cv;
                    lpart = fmaf(hv.x, q2.x, lpart);
                    lpart = fmaf(hv.y, q2.y, lpart);
                }
#pragma unroll
                for (int off = 32; off > 0; off >>= 1) lpart += __shfl_down(lpart, off);
                if (lane == 0) s_plog[slot] = lpart;
            }
            __syncthreads();

            // Phase B: argmax over j < actb (first-index tie-break)
            const int actb = lenb - 1 - step;
            const int merge = actb >= 1;
            if (tid < 64) {
                float v = -1e30f;
                int idx = tid;
                if (tid < actb && tid < 31) v = s_plog[s_pidx[tid]];
#pragma unroll
                for (int off = 32; off > 0; off >>= 1) {
                    float ov = __shfl_down(v, off);
                    int   oi = __shfl_down(idx, off);
                    if (ov > v || (ov == v && oi < idx)) { v = ov; idx = oi; }
                }
                if (tid == 0) s_k = idx;
            }
            __syncthreads();
            const int k = s_k;
            const int last = (step == NSTEPS - 1);
            const int NSLOT = 33 + step;

            // Phase C: node output, fresh h-slot write, final hf/cf
            float* noderow = out + 2 * BH + ((size_t)b * 63 + 32 + step) * NHID;
            if (merge) {
                const int kslot = s_pidx[k];
                const int csl = s_cidx[k];
                if (tid < 128) {
                    const int h0 = tid * 4;
                    const size_t pb = ((size_t)kslot * NB + b) * NHID + h0;
                    float4 x4 = *(const float4*)&pnh[pb];
                    float4 c4 = *(const float4*)&pnc[pb];
                    half4 hv, lv;
#pragma unroll
                    for (int i = 0; i < 4; ++i) {
                        float x = (&x4.x)[i];
                        _Float16 hh = (_Float16)x;
                        hv[i] = hh;
                        lv[i] = (_Float16)((x - (float)hh) * 2048.f);
                    }
                    const size_t so = ((size_t)NSLOT * NB + b) * NHID + h0;
                    st_sc64(&hHi[so], __builtin_bit_cast(u64, hv));
                    st_sc64(&hLo[so], __builtin_bit_cast(u64, lv));
                    *(float4*)&cSt[((size_t)csl * NB + b) * NHID + h0] = c4;
                    *(float4*)&noderow[h0] = x4;
                    if (last) {
                        *(float4*)&out[b * NHID + h0] = x4;
                        *(float4*)&out[BH + b * NHID + h0] = c4;
                    }
                }
            } else {
                const int s0p = s_pidx[0], s0h = s_hidx[0], s0c = s_cidx[0];
                if (tid < 128) {
                    const int h0 = tid * 4;
                    if (!last) {
                        *(float4*)&noderow[h0] =
                            *(const float4*)&pnh[((size_t)s0p * NB + b) * NHID + h0];
                    } else {
                        const size_t so = ((size_t)s0h * NB + b) * NHID + h0;
                        half4 hv = __builtin_bit_cast(half4, ld_sc64(&hHi[so]));
                        half4 lv = __builtin_bit_cast(half4, ld_sc64(&hLo[so]));
                        float4 x4;
#pragma unroll
                        for (int i = 0; i < 4; ++i)
                            (&x4.x)[i] = (float)hv[i] + (float)lv[i] * INV2048;
                        *(float4*)&noderow[h0] = x4;
                        *(float4*)&out[b * NHID + h0] = x4;
                        *(float4*)&out[BH + b * NHID + h0] =
                            *(const float4*)&cSt[((size_t)s0c * NB + b) * NHID + h0];
                    }
                }
            }
            __syncthreads();   // drain h-state stores before publishing entries

            // Phase D: publish stamped entries for step+1, shift bookkeeping
            if (tid == 0) {
                const unsigned dummy = pack_e(b, 31, HSLOT_Z, HSLOT_Z);
                if (merge) {
                    unsigned e1 = pack_e(b, s_pidx[k], NSLOT,
                                         (k + 2 <= 31) ? s_hidx[k + 2] : HSLOT_Z);
                    unsigned e0 = (k >= 1)
                        ? pack_e(b, s_pidx[k - 1], s_hidx[k - 1], NSLOT) : dummy;
                    if (!last) {
                        const u64 st = (u64)(step + 1) << 32;
                        st_sc64(&elist[2 * b],     (u64)e0 | st);
                        st_sc64(&elist[2 * b + 1], (u64)e1 | st);
                    }
                    const int recycP = s_pidx[k + 1];
                    for (int j2 = k + 1; j2 <= 29; ++j2) s_pidx[j2] = s_pidx[j2 + 1];
                    if (k < 30) s_pidx[30] = recycP;
                    s_hidx[k] = NSLOT;
                    for (int pp = k + 1; pp <= 30; ++pp) s_hidx[pp] = s_hidx[pp + 1];
                    s_hidx[31] = HSLOT_Z;
                    for (int pp = k + 1; pp <= 30; ++pp) s_cidx[pp] = s_cidx[pp + 1];
                    s_cidx[31] = HSLOT_Z;
                    s_prevk = k;
                } else {
                    if (!last) {
                        const u64 st = (u64)(step + 1) << 32;
                        st_sc64(&elist[2 * b],     (u64)dummy | st);
                        st_sc64(&elist[2 * b + 1], (u64)dummy | st);
                    }
                    s_prevk = -1;
                }
            }
        }
    }
}

extern "C" void kernel_launch(void* const* d_in, const int* in_sizes, int n_in,
                              void* d_out, int out_size, void* d_ws, size_t ws_size,
                              hipStream_t stream) {
    const float* inp    = (const float*)d_in[0];
    const int*   length = (const int*)d_in[1];
    const float* W_word = (const float*)d_in[2];
    const float* b_word = (const float*)d_in[3];
    const float* W_comp = (const float*)d_in[4];
    const float* b_comp = (const float*)d_in[5];
    const float* q      = (const float*)d_in[6];
    float* out = (float*)d_out;
    float* ws  = (float*)d_ws;

    float*     graw = ws + OFF_GRAW;
    float*     pnh  = ws + OFF_PNH;
    float*     pnc  = ws + OFF_PNC;
    float*     cSt  = ws + OFF_CST;
    _Float16*  hHi  = (_Float16*)(ws + OFF_HHI);
    _Float16*  hLo  = (_Float16*)(ws + OFF_HLO);
    _Float16*  Wth  = (_Float16*)(ws + OFF_WTH);
    _Float16*  Wtl  = (_Float16*)(ws + OFF_WTL);
    int*       ireg = (int*)(ws + OFF_INT);
    u64*       elist = (u64*)(ws + OFF_LIST);

    init_kernel<<<34, 256, 0, stream>>>(ireg, elist, hHi, hLo, cSt);
    wsplit_kernel<<<dim3(NC5 / 32, 1024 / 32), 256, 0, stream>>>(W_comp, Wth, Wtl);
    word_gemm64<<<dim3(16, 16), 256, 0, stream>>>(inp, W_word, b_word,
                                                  hHi, hLo, cSt, out);
    tree_loop<<<NBLK, 256, 0, stream>>>(hHi, hLo, Wth, Wtl, graw, b_comp, q, length,
                                        pnh, pnc, cSt, elist, ireg, out);
}